// Round 10
// baseline (406.384 us; speedup 1.0000x reference)
//
#include <hip/hip_runtime.h>
#include <math.h>

// Problem constants (from reference)
#define NWG   16          // NW groups
#define NSTEP 16          // 1 + NG + NF sequences per group
#define NGE   5
#define T_LEN 400
#define DIM   64
#define GAMMA 5.0f
#define BIGV  1e10f

#define BLOCK 448         // 7 waves; lane slot iA = 63*w + l (1-lane halo/wave)

// softmin in base-2: exp2/log2 native HW ops, gamma folded into constants
#define NIG2  (-0.28853900817779268f)   // -1/(GAMMA*ln2)
#define GLN2  (3.4657359027997265f)     //  GAMMA*ln2

// ---------------------------------------------------------------------------
// Fused cost + soft-DTW wavefront, one block per (anchor, seq) pair.
// 2x1 column-pair blocking (round-7 structure, passed absmax=0) PLUS:
//  * B-row REGISTER PREFETCH: B is static in LDS, so the row for phase ph+1
//    (c+2) is issued during phase ph right after the dot consumes the current
//    row. Read latency retires under softmin+barrier -> LDS off critical path.
//  * base-2 softmin (v_exp_f32/v_log_f32 are native 2^x / log2x).
// Deps/boundaries identical to the verified round-7 kernel.
// ---------------------------------------------------------------------------
__launch_bounds__(BLOCK, 2)
__global__ void sdtw_kernel(const float* __restrict__ data,
                            const int* __restrict__ lens,
                            float* __restrict__ dists)
{
    __shared__ float Blds[T_LEN * DIM];        // 102,400 B (swizzled)
    __shared__ float bnorm[T_LEN];             // 1,600 B
    __shared__ float Rbuf[4][T_LEN + 1];       // 6,416 B

    const int p   = blockIdx.x;
    const int tid = threadIdx.x;
    const int w   = tid >> 6;
    const int l   = tid & 63;
    const int iA  = 63 * w + l;        // cellA row; 0 => boundary row R[0][*]
    const int anchor = (p / NSTEP) * NSTEP;

    const float* __restrict__ Bg = data + (size_t)p      * (T_LEN * DIM);
    const float* __restrict__ Ag = data + (size_t)anchor * (T_LEN * DIM);

    // ---- stage B into LDS (coalesced global read, swizzled LDS write) ----
    for (int idx = tid; idx < T_LEN * (DIM / 4); idx += BLOCK) {
        const int c  = idx >> 4;       // B row
        const int cc = idx & 15;       // 16B chunk within row
        const float4 v = reinterpret_cast<const float4*>(Bg)[idx];
        const int x  = cc ^ (c & 7);   // swizzled chunk
        *reinterpret_cast<float4*>(&Blds[c * DIM + x * 4]) = v;
    }

    // ---- A rows iA-1 (cellA) and iA (cellB) into registers + norms ----
    float4 Aa[16], Ab[16];
    float  anA = 0.f, anB = 0.f;
    {
        const int ra = min(max(iA - 1, 0), T_LEN - 1);   // clamp: inactive lanes
        const int rb = min(iA, T_LEN - 1);
        const float4* __restrict__ pa =
            reinterpret_cast<const float4*>(Ag + (size_t)ra * DIM);
        const float4* __restrict__ pb =
            reinterpret_cast<const float4*>(Ag + (size_t)rb * DIM);
        #pragma unroll
        for (int cc = 0; cc < 16; ++cc) {
            Aa[cc] = pa[cc];
            Ab[cc] = pb[cc];
            anA += Aa[cc].x*Aa[cc].x + Aa[cc].y*Aa[cc].y
                 + Aa[cc].z*Aa[cc].z + Aa[cc].w*Aa[cc].w;
            anB += Ab[cc].x*Ab[cc].x + Ab[cc].y*Ab[cc].y
                 + Ab[cc].z*Ab[cc].z + Ab[cc].w*Ab[cc].w;
        }
    }
    __syncthreads();   // B resident

    // ---- ||B_c||^2 from LDS (lane c reads its own row; conflict-free) ----
    if (tid < T_LEN) {
        const int c = tid;
        float s = 0.f;
        #pragma unroll
        for (int cc = 0; cc < 16; ++cc) {
            const float4 b = *reinterpret_cast<const float4*>(
                &Blds[c * DIM + ((cc ^ (c & 7)) * 4)]);
            s += b.x*b.x + b.y*b.y + b.z*b.z + b.w*b.w;
        }
        bnorm[c] = s;
    }

    // ---- init diag buffers 0 (R[0][0]=0, rest BIG) and 1 (all BIG) ----
    for (int idx = tid; idx <= T_LEN; idx += BLOCK) {
        Rbuf[0][idx] = (idx == 0) ? 0.f : BIGV;
        Rbuf[1][idx] = BIGV;
    }
    __syncthreads();

    const int la = lens[anchor];       // [200, 400]
    const int lb = lens[p];
    const int kt = la + lb;            // target diag, [400, 800]
    const int P  = kt >> 1;            // phases: diags (2, 3) .. (2P, 2P+1)
    float saved = 0.f;
    bool  have  = false;

    // ---- prefetch the B row for phase 1 (k=2): c0 = 1 - iA ----
    float4 Br[16];
    {
        const int c0 = 1 - iA;
        if (c0 >= 0 && c0 < lb) {
            const float* __restrict__ Brow = &Blds[c0 * DIM];
            const int xr = (c0 & 7) * 4;
            #pragma unroll
            for (int cc = 0; cc < 16; ++cc)
                Br[cc] = *reinterpret_cast<const float4*>(&Brow[(cc * 4) ^ xr]);
        }
    }

    for (int ph = 1; ph <= P; ++ph) {
        const int  k     = 2 * ph;                 // cellA diag (cellB: k+1)
        const int  c     = k - iA - 1;             // shared B row = jA-1 = jB-1
        const bool colOK = (c >= 0) && (c < lb);
        const bool aAct  = colOK && (iA >= 1) && (iA <= la);
        const bool bAct  = colOK && (l < 63) && (iA + 1 <= la);

        float p1vr = BIGV;       // R[iA][k-1-iA]: cellA p1v AND cellB p2
        float dA = 0.f, dB = 0.f, bn = 0.f;
        if (aAct || bAct) {
            p1vr = Rbuf[(k - 1) & 3][iA];
            bn   = bnorm[c];
            #pragma unroll
            for (int cc = 0; cc < 16; ++cc) {
                const float4 b = Br[cc];           // prefetched registers
                dA = fmaf(Aa[cc].x, b.x, dA); dB = fmaf(Ab[cc].x, b.x, dB);
                dA = fmaf(Aa[cc].y, b.y, dA); dB = fmaf(Ab[cc].y, b.y, dB);
                dA = fmaf(Aa[cc].z, b.z, dA); dB = fmaf(Ab[cc].z, b.z, dB);
                dA = fmaf(Aa[cc].w, b.w, dA); dB = fmaf(Ab[cc].w, b.w, dB);
            }
        }

        // ---- prefetch next phase's B row (c+2); B static -> no hazard ----
        {
            const int cn = c + 2;
            if (cn >= 0 && cn < lb) {
                const float* __restrict__ Brow = &Blds[cn * DIM];
                const int xr = (cn & 7) * 4;
                #pragma unroll
                for (int cc = 0; cc < 16; ++cc)
                    Br[cc] = *reinterpret_cast<const float4*>(&Brow[(cc * 4) ^ xr]);
            }
        }

        float vA = BIGV;
        if (aAct) {
            const float p2s = Rbuf[(k - 2) & 3][iA - 1];   // R[iA-1][jA-1]
            const float p1s = Rbuf[(k - 1) & 3][iA - 1];   // R[iA-1][jA]
            const float a  = p2s  * NIG2;
            const float b2 = p1s  * NIG2;
            const float c2 = p1vr * NIG2;
            float m = fmaxf(fmaxf(a, b2), c2);
            float s = __builtin_amdgcn_exp2f(a - m) + __builtin_amdgcn_exp2f(b2 - m)
                    + __builtin_amdgcn_exp2f(c2 - m);
            vA = (anA + bn - 2.f * dA) - GLN2 * (__builtin_amdgcn_logf(s) + m);
        }

        // wave-uniform shuffle: lane l receives vA of lane l+1
        // (= cellA of row iA+1 = R[iB][jB-1]); vA defined (BIG) on all lanes.
        const float vAn = __shfl_down(vA, 1);

        float vB = BIGV;
        if (bAct) {
            // cellB (iA+1, jB): p2 = p1vr, p1s = own vA, p1v = vAn
            const float a  = p1vr * NIG2;
            const float b2 = vA   * NIG2;
            const float c2 = vAn  * NIG2;
            float m = fmaxf(fmaxf(a, b2), c2);
            float s = __builtin_amdgcn_exp2f(a - m) + __builtin_amdgcn_exp2f(b2 - m)
                    + __builtin_amdgcn_exp2f(c2 - m);
            vB = (anB + bn - 2.f * dB) - GLN2 * (__builtin_amdgcn_logf(s) + m);
        }

        // capture R[la][lb] (unique primary rep: l < 63)
        if (k == kt     && iA == la     && l < 63) { saved = vA; have = true; }
        if (k + 1 == kt && iA + 1 == la && l < 63) { saved = vB; have = true; }

        // write-back (write buffers {k&3,(k+1)&3} disjoint from read buffers)
        if (iA <= T_LEN)               Rbuf[k & 3][iA] = vA;          // iA=0 -> BIG
        if (l < 63 && iA + 1 <= T_LEN) Rbuf[(k + 1) & 3][iA + 1] = vB;
        if (tid == BLOCK - 1)          Rbuf[(k + 1) & 3][0] = BIGV;   // R[0][k+1]
        __syncthreads();
    }

    if (have) dists[p] = saved / (float)kt;
}

// ---------------------------------------------------------------------------
// Loss epilogue (one wave). Exact-zero semantics of `nz` preserved.
// ---------------------------------------------------------------------------
__global__ void loss_kernel(const float* __restrict__ dists,
                            const float* __restrict__ margin,
                            float* __restrict__ out)
{
    const int g = threadIdx.x;
    float lv = 0.f;
    if (g < NWG) {
        const float* __restrict__ d = dists + g * NSTEP;
        const float aa = d[0];
        const float mg = margin[0];
        float s = 0.f;
        int   nz = 1;
        #pragma unroll
        for (int j = 1; j <= NGE; ++j) {
            const float v = d[j] - aa;
            s += v;
            nz += (v != 0.f);
        }
        #pragma unroll
        for (int j = 1 + NGE; j < NSTEP; ++j) {
            float v = mg - (d[j] - aa);
            v = fmaxf(v, 0.f);
            s += v;
            nz += (v != 0.f);
        }
        lv = s / (float)nz;
    }
    lv += __shfl_down(lv, 8);
    lv += __shfl_down(lv, 4);
    lv += __shfl_down(lv, 2);
    lv += __shfl_down(lv, 1);
    if (g == 0) out[0] = lv / (float)NWG;
}

extern "C" void kernel_launch(void* const* d_in, const int* in_sizes, int n_in,
                              void* d_out, int out_size, void* d_ws, size_t ws_size,
                              hipStream_t stream) {
    const float* data   = (const float*)d_in[0];
    const float* margin = (const float*)d_in[1];
    const int*   lens   = (const int*)d_in[2];
    float* dists = (float*)d_ws;          // 256 floats of scratch

    sdtw_kernel<<<NWG * NSTEP, BLOCK, 0, stream>>>(data, lens, dists);
    loss_kernel<<<1, 64, 0, stream>>>(dists, margin, (float*)d_out);
}